// Round 15
// baseline (57.952 us; speedup 1.0000x reference)
//
#include <hip/hip_runtime.h>
#include <math.h>

#define BB 32
#define NN 4096
#define DD 512
#define CC 5
#define SSEG 16   // 32*16 = 512 blocks = exactly 2 resident blocks/CU (launch_bounds 256,2)

// Native 4-float vector for nontemporal builtins (HIP_vector_type is a class
// and is rejected by __builtin_nontemporal_{load,store}).
typedef float floatx4 __attribute__((ext_vector_type(4)));

// DPP-add step: v += dpp_permuted(v). bound_ctrl=1 -> 0 for lanes w/o source.
#define DPP_ADD(v, ctrl, rmask)                                                 \
    (v) += __int_as_float(__builtin_amdgcn_update_dpp(                          \
        0, __float_as_int(v), (ctrl), (rmask), 0xF, true))

// Canonical CDNA wave64 all-reduce via DPP only (no DS pipe), result made
// wave-uniform via readlane 63.
static __device__ __forceinline__ float wave_allreduce_add(float v)
{
    DPP_ADD(v, 0x111, 0xF);   // row_shr:1
    DPP_ADD(v, 0x112, 0xF);   // row_shr:2
    DPP_ADD(v, 0x114, 0xF);   // row_shr:4
    DPP_ADD(v, 0x118, 0xF);   // row_shr:8
    DPP_ADD(v, 0x142, 0xA);   // row_bcast:15 -> rows 1,3
    DPP_ADD(v, 0x143, 0xC);   // row_bcast:31 -> rows 2,3
    return __int_as_float(__builtin_amdgcn_readlane(__float_as_int(v), 63));
}

// Hot-loop bodies as macros over kernel-scope arrays, fully unrolled
// compile-time indices -> guaranteed VGPR residency (R6/R8 lesson).
// x is streamed exactly once -> nontemporal loads (no L2/L3 retention).
#define LOADB(XA, XB, row)                                                      \
    {                                                                           \
        _Pragma("unroll")                                                       \
        for (int _r = 0; _r < 4; ++_r) {                                        \
            const float* _xr = xb_ + (size_t)((row) + _r) * DD;                 \
            XA[_r] = __builtin_nontemporal_load(                                \
                reinterpret_cast<const floatx4*>(_xr + d0));                    \
            XB[_r] = __builtin_nontemporal_load(                                \
                reinterpret_cast<const floatx4*>(_xr + d1));                    \
        }                                                                       \
    }

#define PROCB(XA, XB)                                                           \
    {                                                                           \
        float _e[4][CC];                                                        \
        _Pragma("unroll")                                                       \
        for (int _r = 0; _r < 4; ++_r) {                                        \
            const float _xv[8] = {XA[_r].x, XA[_r].y, XA[_r].z, XA[_r].w,       \
                                  XB[_r].x, XB[_r].y, XB[_r].z, XB[_r].w};      \
            _Pragma("unroll")                                                   \
            for (int _c = 0; _c < CC; ++_c) {                                   \
                float _s = 0.0f;                                                \
                _Pragma("unroll")                                               \
                for (int _j = 0; _j < 4; ++_j)                                  \
                    _s = fmaf(_xv[_j], wal[_j * CC + _c], _s);                  \
                _Pragma("unroll")                                               \
                for (int _j = 0; _j < 4; ++_j)                                  \
                    _s = fmaf(_xv[4 + _j], wah[_j * CC + _c], _s);              \
                _e[_r][_c] = _s;                                                \
            }                                                                   \
        }                                                                       \
        _Pragma("unroll")                                                       \
        for (int _r = 0; _r < 4; ++_r)                                          \
            _Pragma("unroll")                                                   \
            for (int _c = 0; _c < CC; ++_c)                                     \
                _e[_r][_c] = wave_allreduce_add(_e[_r][_c]);                    \
        float _mb[CC];                                                          \
        _Pragma("unroll")                                                       \
        for (int _c = 0; _c < CC; ++_c)                                         \
            _mb[_c] = fmaxf(fmaxf(_e[0][_c], _e[1][_c]),                        \
                            fmaxf(_e[2][_c], _e[3][_c]));                       \
        bool _raise = false;                                                    \
        _Pragma("unroll")                                                       \
        for (int _c = 0; _c < CC; ++_c) _raise = _raise || (_mb[_c] > m[_c]);   \
        if (__ballot(_raise) != 0ull) {                                         \
            _Pragma("unroll")                                                   \
            for (int _c = 0; _c < CC; ++_c) {                                   \
                const float _mn = fmaxf(m[_c], _mb[_c]);                        \
                const float _sc = __expf(m[_c] - _mn);                          \
                l[_c] *= _sc;                                                   \
                _Pragma("unroll")                                               \
                for (int _j = 0; _j < 8; ++_j) acc[_c][_j] *= _sc;              \
                m[_c] = _mn;                                                    \
            }                                                                   \
        }                                                                       \
        _Pragma("unroll")                                                       \
        for (int _r = 0; _r < 4; ++_r) {                                        \
            const float _xv[8] = {XA[_r].x, XA[_r].y, XA[_r].z, XA[_r].w,       \
                                  XB[_r].x, XB[_r].y, XB[_r].z, XB[_r].w};      \
            _Pragma("unroll")                                                   \
            for (int _c = 0; _c < CC; ++_c) {                                   \
                const float _p = __expf(_e[_r][_c] - m[_c]);                    \
                l[_c] += _p;                                                    \
                _Pragma("unroll")                                               \
                for (int _j = 0; _j < 8; ++_j)                                  \
                    acc[_c][_j] = fmaf(_p, _xv[_j], acc[_c][_j]);               \
            }                                                                   \
        }                                                                       \
    }

// Pass 1 (R7 structure, best measured): ping-pong double-buffered 4-row
// batches, peeled tail, 2 blocks/CU; nontemporal x loads.
__global__ __launch_bounds__(256, 2)
void capsule_pass1(const float* __restrict__ x, const float* __restrict__ Wa,
                   float* __restrict__ acc_ws, float* __restrict__ ml_ws)
{
    const int blk  = blockIdx.x;
    const int b    = blk / SSEG;
    const int seg  = blk % SSEG;
    const int tid  = threadIdx.x;
    const int lane = tid & 63;
    const int wid  = tid >> 6;   // 0..3

    const int d0 = lane * 4;
    const int d1 = 256 + lane * 4;

    float wal[20], wah[20];
    {
        const float4* pl = reinterpret_cast<const float4*>(Wa + d0 * CC);
        const float4* ph = reinterpret_cast<const float4*>(Wa + d1 * CC);
#pragma unroll
        for (int q = 0; q < 5; ++q) {
            float4 a = pl[q];
            wal[q * 4 + 0] = a.x; wal[q * 4 + 1] = a.y;
            wal[q * 4 + 2] = a.z; wal[q * 4 + 3] = a.w;
            float4 b4 = ph[q];
            wah[q * 4 + 0] = b4.x; wah[q * 4 + 1] = b4.y;
            wah[q * 4 + 2] = b4.z; wah[q * 4 + 3] = b4.w;
        }
    }

    float acc[CC][8];
    float m[CC], l[CC];
#pragma unroll
    for (int c = 0; c < CC; ++c) {
        m[c] = -INFINITY;
        l[c] = 0.0f;
#pragma unroll
        for (int j = 0; j < 8; ++j) acc[c][j] = 0.0f;
    }

    const int rs  = seg * (NN / SSEG);
    const int ws_ = rs + wid * (NN / SSEG / 4);
    const int we_ = ws_ + (NN / SSEG / 4);

    const float* xb_ = x + (size_t)b * NN * DD;

    floatx4 xaA[4], xbA[4], xaB[4], xbB[4];
    LOADB(xaA, xbA, ws_);
    int i0 = ws_;
    for (; i0 + 8 < we_; i0 += 8) {        // last pair peeled (no dead prefetch)
        LOADB(xaB, xbB, i0 + 4);
        PROCB(xaA, xbA);
        LOADB(xaA, xbA, i0 + 8);
        PROCB(xaB, xbB);
    }
    LOADB(xaB, xbB, i0 + 4);
    PROCB(xaA, xbA);
    PROCB(xaB, xbB);

    // ---- combine the 4 waves ----
    __shared__ float s_ml[4][CC][2];
    __shared__ float s_acc[CC][DD];   // 10 KB

    if (lane == 0) {
#pragma unroll
        for (int c = 0; c < CC; ++c) {
            s_ml[wid][c][0] = m[c];
            s_ml[wid][c][1] = l[c];
        }
    }
    __syncthreads();

    float mb2[CC], lb2[CC], cw[CC];
#pragma unroll
    for (int c = 0; c < CC; ++c) {
        float mm = s_ml[0][c][0];
#pragma unroll
        for (int w = 1; w < 4; ++w) mm = fmaxf(mm, s_ml[w][c][0]);
        mb2[c] = mm;
        float ll = 0.0f;
#pragma unroll
        for (int w = 0; w < 4; ++w) ll += __expf(s_ml[w][c][0] - mm) * s_ml[w][c][1];
        lb2[c] = ll;
        cw[c] = __expf(s_ml[wid][c][0] - mm);
    }

    for (int w = 0; w < 4; ++w) {
        if (wid == w) {
#pragma unroll
            for (int c = 0; c < CC; ++c) {
#pragma unroll
                for (int j = 0; j < 8; ++j) {
                    const int d = (j < 4) ? (d0 + j) : (d1 + j - 4);
                    const float v = acc[c][j] * cw[c];
                    if (w == 0) s_acc[c][d] = v;
                    else        s_acc[c][d] += v;
                }
            }
        }
        __syncthreads();
    }

    // nontemporal partial write (consumed once by pass2, no reuse here)
    floatx4* accp = reinterpret_cast<floatx4*>(acc_ws + (size_t)blk * CC * DD);
    const floatx4* sa = reinterpret_cast<const floatx4*>(&s_acc[0][0]);
    for (int idx = tid; idx < CC * DD / 4; idx += 256)
        __builtin_nontemporal_store(sa[idx], &accp[idx]);
    if (tid < CC) {
        ml_ws[((size_t)blk * CC + tid) * 2 + 0] = mb2[tid];
        ml_ws[((size_t)blk * CC + tid) * 2 + 1] = lb2[tid];
    }
}

// Pass 2: one block per (b,c), 512 threads, one d per thread. All 16 segment
// loads independent & fully unrolled (16-deep MLP); weights folded once.
__global__ __launch_bounds__(512)
void capsule_pass2(const float* __restrict__ acc_ws, const float* __restrict__ ml_ws,
                   const float* __restrict__ lin_w, const float* __restrict__ lin_b,
                   float* __restrict__ p_out, float* __restrict__ v_out,
                   float* __restrict__ r_out)
{
    const int bc  = blockIdx.x;          // 0..B*C-1
    const int b   = bc / CC;
    const int c   = bc % CC;
    const int tid = threadIdx.x;         // 0..511 = d index
    const int lane = tid & 63;
    const int wid  = tid >> 6;           // 0..7

    __shared__ float s_red[8];
    __shared__ float s_p;

    // all threads redundantly compute the (identical) segment weights
    float mg = -INFINITY;
#pragma unroll
    for (int s = 0; s < SSEG; ++s)
        mg = fmaxf(mg, ml_ws[(((size_t)b * SSEG + s) * CC + c) * 2]);
    float lg = 0.0f;
    float w[SSEG];
#pragma unroll
    for (int s = 0; s < SSEG; ++s) {
        const float mw = ml_ws[(((size_t)b * SSEG + s) * CC + c) * 2];
        const float lw = ml_ws[(((size_t)b * SSEG + s) * CC + c) * 2 + 1];
        w[s] = __expf(mw - mg);
        lg += w[s] * lw;
    }
    const float inv_l = 1.0f / lg;
#pragma unroll
    for (int s = 0; s < SSEG; ++s) w[s] *= inv_l;

    // 16 independent loads (one per segment), then weighted sum
    const float* ap0 = acc_ws + (((size_t)b * SSEG) * CC + c) * DD + tid;
    float xs[SSEG];
#pragma unroll
    for (int s = 0; s < SSEG; ++s)
        xs[s] = ap0[(size_t)s * CC * DD];
    float v = 0.0f;
#pragma unroll
    for (int s = 0; s < SSEG; ++s)
        v = fmaf(w[s], xs[s], v);

    v_out[(size_t)bc * DD + tid] = v;

    // dot(v, lin_w) across 512 threads: DPP wave-reduce + LDS combine
    float part = v * lin_w[tid];
    DPP_ADD(part, 0x111, 0xF);
    DPP_ADD(part, 0x112, 0xF);
    DPP_ADD(part, 0x114, 0xF);
    DPP_ADD(part, 0x118, 0xF);
    DPP_ADD(part, 0x142, 0xA);
    DPP_ADD(part, 0x143, 0xC);
    if (lane == 63) s_red[wid] = part;
    __syncthreads();
    if (tid == 0) {
        float dot = lin_b[0];
#pragma unroll
        for (int q = 0; q < 8; ++q) dot += s_red[q];
        s_p = tanhf(dot);
        p_out[bc] = s_p;
    }
    __syncthreads();
    r_out[(size_t)bc * DD + tid] = s_p * v;
}

extern "C" void kernel_launch(void* const* d_in, const int* in_sizes, int n_in,
                              void* d_out, int out_size, void* d_ws, size_t ws_size,
                              hipStream_t stream) {
    const float* x   = (const float*)d_in[0];
    const float* Wa  = (const float*)d_in[1];
    const float* lw  = (const float*)d_in[2];
    const float* lb  = (const float*)d_in[3];

    float* out   = (float*)d_out;
    float* p_out = out;                       // (B, C)
    float* v_out = out + BB * CC;             // (B, C, D)
    float* r_out = v_out + BB * CC * DD;      // (B, C, D)

    float* acc_ws = (float*)d_ws;                           // B*SSEG*C*D floats
    float* ml_ws  = acc_ws + (size_t)BB * SSEG * CC * DD;   // B*SSEG*C*2 floats

    capsule_pass1<<<dim3(BB * SSEG), dim3(256), 0, stream>>>(x, Wa, acc_ws, ml_ws);
    capsule_pass2<<<dim3(BB * CC), dim3(512), 0, stream>>>(acc_ws, ml_ws, lw, lb,
                                                           p_out, v_out, r_out);
}

// Round 16
// 57.662 us; speedup vs baseline: 1.0050x; 1.0050x over previous
//
#include <hip/hip_runtime.h>
#include <math.h>

#define BB 32
#define NN 4096
#define DD 512
#define CC 5
#define SSEG 16   // 32*16 = 512 blocks = exactly 2 resident blocks/CU (launch_bounds 256,2)

// DPP-add step: v += dpp_permuted(v). bound_ctrl=1 -> 0 for lanes w/o source.
#define DPP_ADD(v, ctrl, rmask)                                                 \
    (v) += __int_as_float(__builtin_amdgcn_update_dpp(                          \
        0, __float_as_int(v), (ctrl), (rmask), 0xF, true))

// Canonical CDNA wave64 all-reduce via DPP only (no DS pipe), result made
// wave-uniform via readlane 63.
static __device__ __forceinline__ float wave_allreduce_add(float v)
{
    DPP_ADD(v, 0x111, 0xF);   // row_shr:1
    DPP_ADD(v, 0x112, 0xF);   // row_shr:2
    DPP_ADD(v, 0x114, 0xF);   // row_shr:4
    DPP_ADD(v, 0x118, 0xF);   // row_shr:8
    DPP_ADD(v, 0x142, 0xA);   // row_bcast:15 -> rows 1,3
    DPP_ADD(v, 0x143, 0xC);   // row_bcast:31 -> rows 2,3
    return __int_as_float(__builtin_amdgcn_readlane(__float_as_int(v), 63));
}

// Hot-loop bodies as macros over kernel-scope arrays, fully unrolled
// compile-time indices -> guaranteed VGPR residency (R6/R8 lesson).
// Plain cached loads: NT hints measured -1.8us (R15), reverted.
#define LOADB(XA, XB, row)                                                      \
    {                                                                           \
        _Pragma("unroll")                                                       \
        for (int _r = 0; _r < 4; ++_r) {                                        \
            const float* _xr = xb_ + (size_t)((row) + _r) * DD;                 \
            XA[_r] = *reinterpret_cast<const float4*>(_xr + d0);                \
            XB[_r] = *reinterpret_cast<const float4*>(_xr + d1);                \
        }                                                                       \
    }

#define PROCB(XA, XB)                                                           \
    {                                                                           \
        float _e[4][CC];                                                        \
        _Pragma("unroll")                                                       \
        for (int _r = 0; _r < 4; ++_r) {                                        \
            const float _xv[8] = {XA[_r].x, XA[_r].y, XA[_r].z, XA[_r].w,       \
                                  XB[_r].x, XB[_r].y, XB[_r].z, XB[_r].w};      \
            _Pragma("unroll")                                                   \
            for (int _c = 0; _c < CC; ++_c) {                                   \
                float _s = 0.0f;                                                \
                _Pragma("unroll")                                               \
                for (int _j = 0; _j < 4; ++_j)                                  \
                    _s = fmaf(_xv[_j], wal[_j * CC + _c], _s);                  \
                _Pragma("unroll")                                               \
                for (int _j = 0; _j < 4; ++_j)                                  \
                    _s = fmaf(_xv[4 + _j], wah[_j * CC + _c], _s);              \
                _e[_r][_c] = _s;                                                \
            }                                                                   \
        }                                                                       \
        _Pragma("unroll")                                                       \
        for (int _r = 0; _r < 4; ++_r)                                          \
            _Pragma("unroll")                                                   \
            for (int _c = 0; _c < CC; ++_c)                                     \
                _e[_r][_c] = wave_allreduce_add(_e[_r][_c]);                    \
        float _mb[CC];                                                          \
        _Pragma("unroll")                                                       \
        for (int _c = 0; _c < CC; ++_c)                                         \
            _mb[_c] = fmaxf(fmaxf(_e[0][_c], _e[1][_c]),                        \
                            fmaxf(_e[2][_c], _e[3][_c]));                       \
        bool _raise = false;                                                    \
        _Pragma("unroll")                                                       \
        for (int _c = 0; _c < CC; ++_c) _raise = _raise || (_mb[_c] > m[_c]);   \
        if (__ballot(_raise) != 0ull) {                                         \
            _Pragma("unroll")                                                   \
            for (int _c = 0; _c < CC; ++_c) {                                   \
                const float _mn = fmaxf(m[_c], _mb[_c]);                        \
                const float _sc = __expf(m[_c] - _mn);                          \
                l[_c] *= _sc;                                                   \
                _Pragma("unroll")                                               \
                for (int _j = 0; _j < 8; ++_j) acc[_c][_j] *= _sc;              \
                m[_c] = _mn;                                                    \
            }                                                                   \
        }                                                                       \
        _Pragma("unroll")                                                       \
        for (int _r = 0; _r < 4; ++_r) {                                        \
            const float _xv[8] = {XA[_r].x, XA[_r].y, XA[_r].z, XA[_r].w,       \
                                  XB[_r].x, XB[_r].y, XB[_r].z, XB[_r].w};      \
            _Pragma("unroll")                                                   \
            for (int _c = 0; _c < CC; ++_c) {                                   \
                const float _p = __expf(_e[_r][_c] - m[_c]);                    \
                l[_c] += _p;                                                    \
                _Pragma("unroll")                                               \
                for (int _j = 0; _j < 8; ++_j)                                  \
                    acc[_c][_j] = fmaf(_p, _xv[_j], acc[_c][_j]);               \
            }                                                                   \
        }                                                                       \
    }

// Pass 1 (R7 structure, best measured): ping-pong double-buffered 4-row
// batches, peeled tail, 2 blocks/CU.
__global__ __launch_bounds__(256, 2)
void capsule_pass1(const float* __restrict__ x, const float* __restrict__ Wa,
                   float* __restrict__ acc_ws, float* __restrict__ ml_ws)
{
    const int blk  = blockIdx.x;
    const int b    = blk / SSEG;
    const int seg  = blk % SSEG;
    const int tid  = threadIdx.x;
    const int lane = tid & 63;
    const int wid  = tid >> 6;   // 0..3

    const int d0 = lane * 4;
    const int d1 = 256 + lane * 4;

    float wal[20], wah[20];
    {
        const float4* pl = reinterpret_cast<const float4*>(Wa + d0 * CC);
        const float4* ph = reinterpret_cast<const float4*>(Wa + d1 * CC);
#pragma unroll
        for (int q = 0; q < 5; ++q) {
            float4 a = pl[q];
            wal[q * 4 + 0] = a.x; wal[q * 4 + 1] = a.y;
            wal[q * 4 + 2] = a.z; wal[q * 4 + 3] = a.w;
            float4 b4 = ph[q];
            wah[q * 4 + 0] = b4.x; wah[q * 4 + 1] = b4.y;
            wah[q * 4 + 2] = b4.z; wah[q * 4 + 3] = b4.w;
        }
    }

    float acc[CC][8];
    float m[CC], l[CC];
#pragma unroll
    for (int c = 0; c < CC; ++c) {
        m[c] = -INFINITY;
        l[c] = 0.0f;
#pragma unroll
        for (int j = 0; j < 8; ++j) acc[c][j] = 0.0f;
    }

    const int rs  = seg * (NN / SSEG);
    const int ws_ = rs + wid * (NN / SSEG / 4);
    const int we_ = ws_ + (NN / SSEG / 4);

    const float* xb_ = x + (size_t)b * NN * DD;

    float4 xaA[4], xbA[4], xaB[4], xbB[4];
    LOADB(xaA, xbA, ws_);
    int i0 = ws_;
    for (; i0 + 8 < we_; i0 += 8) {        // last pair peeled (no dead prefetch)
        LOADB(xaB, xbB, i0 + 4);
        PROCB(xaA, xbA);
        LOADB(xaA, xbA, i0 + 8);
        PROCB(xaB, xbB);
    }
    LOADB(xaB, xbB, i0 + 4);
    PROCB(xaA, xbA);
    PROCB(xaB, xbB);

    // ---- combine the 4 waves ----
    __shared__ float s_ml[4][CC][2];
    __shared__ float s_acc[CC][DD];   // 10 KB

    if (lane == 0) {
#pragma unroll
        for (int c = 0; c < CC; ++c) {
            s_ml[wid][c][0] = m[c];
            s_ml[wid][c][1] = l[c];
        }
    }
    __syncthreads();

    float mb2[CC], lb2[CC], cw[CC];
#pragma unroll
    for (int c = 0; c < CC; ++c) {
        float mm = s_ml[0][c][0];
#pragma unroll
        for (int w = 1; w < 4; ++w) mm = fmaxf(mm, s_ml[w][c][0]);
        mb2[c] = mm;
        float ll = 0.0f;
#pragma unroll
        for (int w = 0; w < 4; ++w) ll += __expf(s_ml[w][c][0] - mm) * s_ml[w][c][1];
        lb2[c] = ll;
        cw[c] = __expf(s_ml[wid][c][0] - mm);
    }

    for (int w = 0; w < 4; ++w) {
        if (wid == w) {
#pragma unroll
            for (int c = 0; c < CC; ++c) {
#pragma unroll
                for (int j = 0; j < 8; ++j) {
                    const int d = (j < 4) ? (d0 + j) : (d1 + j - 4);
                    const float v = acc[c][j] * cw[c];
                    if (w == 0) s_acc[c][d] = v;
                    else        s_acc[c][d] += v;
                }
            }
        }
        __syncthreads();
    }

    float4* accp = reinterpret_cast<float4*>(acc_ws + (size_t)blk * CC * DD);
    const float4* sa = reinterpret_cast<const float4*>(&s_acc[0][0]);
    for (int idx = tid; idx < CC * DD / 4; idx += 256) accp[idx] = sa[idx];
    if (tid < CC) {
        ml_ws[((size_t)blk * CC + tid) * 2 + 0] = mb2[tid];
        ml_ws[((size_t)blk * CC + tid) * 2 + 1] = lb2[tid];
    }
}

// Pass 2: one block per (b,c), 512 threads, one d per thread. All 16 segment
// loads independent & fully unrolled (16-deep MLP); weights folded once.
__global__ __launch_bounds__(512)
void capsule_pass2(const float* __restrict__ acc_ws, const float* __restrict__ ml_ws,
                   const float* __restrict__ lin_w, const float* __restrict__ lin_b,
                   float* __restrict__ p_out, float* __restrict__ v_out,
                   float* __restrict__ r_out)
{
    const int bc  = blockIdx.x;          // 0..B*C-1
    const int b   = bc / CC;
    const int c   = bc % CC;
    const int tid = threadIdx.x;         // 0..511 = d index
    const int lane = tid & 63;
    const int wid  = tid >> 6;           // 0..7

    __shared__ float s_red[8];
    __shared__ float s_p;

    // all threads redundantly compute the (identical) segment weights
    float mg = -INFINITY;
#pragma unroll
    for (int s = 0; s < SSEG; ++s)
        mg = fmaxf(mg, ml_ws[(((size_t)b * SSEG + s) * CC + c) * 2]);
    float lg = 0.0f;
    float w[SSEG];
#pragma unroll
    for (int s = 0; s < SSEG; ++s) {
        const float mw = ml_ws[(((size_t)b * SSEG + s) * CC + c) * 2];
        const float lw = ml_ws[(((size_t)b * SSEG + s) * CC + c) * 2 + 1];
        w[s] = __expf(mw - mg);
        lg += w[s] * lw;
    }
    const float inv_l = 1.0f / lg;
#pragma unroll
    for (int s = 0; s < SSEG; ++s) w[s] *= inv_l;

    // 16 independent loads (one per segment), then weighted sum
    const float* ap0 = acc_ws + (((size_t)b * SSEG) * CC + c) * DD + tid;
    float xs[SSEG];
#pragma unroll
    for (int s = 0; s < SSEG; ++s)
        xs[s] = ap0[(size_t)s * CC * DD];
    float v = 0.0f;
#pragma unroll
    for (int s = 0; s < SSEG; ++s)
        v = fmaf(w[s], xs[s], v);

    v_out[(size_t)bc * DD + tid] = v;

    // dot(v, lin_w) across 512 threads: DPP wave-reduce + LDS combine
    float part = v * lin_w[tid];
    DPP_ADD(part, 0x111, 0xF);
    DPP_ADD(part, 0x112, 0xF);
    DPP_ADD(part, 0x114, 0xF);
    DPP_ADD(part, 0x118, 0xF);
    DPP_ADD(part, 0x142, 0xA);
    DPP_ADD(part, 0x143, 0xC);
    if (lane == 63) s_red[wid] = part;
    __syncthreads();
    if (tid == 0) {
        float dot = lin_b[0];
#pragma unroll
        for (int q = 0; q < 8; ++q) dot += s_red[q];
        s_p = tanhf(dot);
        p_out[bc] = s_p;
    }
    __syncthreads();
    r_out[(size_t)bc * DD + tid] = s_p * v;
}

extern "C" void kernel_launch(void* const* d_in, const int* in_sizes, int n_in,
                              void* d_out, int out_size, void* d_ws, size_t ws_size,
                              hipStream_t stream) {
    const float* x   = (const float*)d_in[0];
    const float* Wa  = (const float*)d_in[1];
    const float* lw  = (const float*)d_in[2];
    const float* lb  = (const float*)d_in[3];

    float* out   = (float*)d_out;
    float* p_out = out;                       // (B, C)
    float* v_out = out + BB * CC;             // (B, C, D)
    float* r_out = v_out + BB * CC * DD;      // (B, C, D)

    float* acc_ws = (float*)d_ws;                           // B*SSEG*C*D floats
    float* ml_ws  = acc_ws + (size_t)BB * SSEG * CC * DD;   // B*SSEG*C*2 floats

    capsule_pass1<<<dim3(BB * SSEG), dim3(256), 0, stream>>>(x, Wa, acc_ws, ml_ws);
    capsule_pass2<<<dim3(BB * CC), dim3(512), 0, stream>>>(acc_ws, ml_ws, lw, lb,
                                                           p_out, v_out, r_out);
}